// Round 6
// baseline (2247.153 us; speedup 1.0000x reference)
//
#include <hip/hip_runtime.h>

typedef __bf16 v8bf __attribute__((ext_vector_type(8)));
typedef float v4f __attribute__((ext_vector_type(4)));
typedef float v4ff __attribute__((ext_vector_type(4)));
typedef unsigned short u16;
typedef unsigned int u32;

#define DEVI __device__ __forceinline__

constexpr int LX = 168, FF = 64;
constexpr int LY = 72, FT = 22, FOUTC = 10;
constexpr int HID = 256;
constexpr int HSTR = 264;   // u16/row for 16x256 tiles (528B = 33*16)
constexpr int UST2 = 40;

// bf16 weight cache layout in d_ws (u16 element offsets; all 16B-aligned)
constexpr int W_EWIH = 0;                      // 768*64
constexpr int W_EWHH = 49152;                  // 768*256
constexpr int W_DWIH = 245760;                 // 768*32
constexpr int W_DWHH = 270336;                 // 768*256
constexpr int W_THW0 = 466944;                 // 128*256
constexpr int W_THW1 = 499712;                 // 2*128
constexpr int W_CLW0 = 499968;                 // 128*256
constexpr int W_CLW1 = 532736;                 // 8*128
constexpr int W_W1F  = 533760;                 // fused padded W1: 16 x 256
constexpr int W_TOTALF = 537856;               // incl. W1F

DEVI u16 f2bf(float f) {
  u32 x; __builtin_memcpy(&x, &f, 4);
  return (u16)((x + 0x7FFFu + ((x >> 16) & 1u)) >> 16);  // RNE (h feeds recurrence)
}
DEVI float sigm(float x) { return __builtin_amdgcn_rcpf(1.f + __expf(-x)); }
DEVI float tanh_(float x) {
  float e = __expf(-2.f * fabsf(x));
  return copysignf((1.f - e) * __builtin_amdgcn_rcpf(1.f + e), x);
}
DEVI float smelu_(float x) {
  if (x >= 1.1f) return x;
  if (x <= -1.1f) return 0.f;
  float u = x + 1.1f;
  return u * u * (1.f / 4.4f);
}
DEVI v8bf ld8(const u16* p) { return *reinterpret_cast<const v8bf*>(p); }
DEVI v4f ldw(const u16* p) { return *reinterpret_cast<const v4f*>(p); }
DEVI v8bf asbf(v4f x) { return __builtin_bit_cast(v8bf, x); }
DEVI void pin(v4f& x) { asm("" : "+v"(x)); }       // defeat rematerialization (r0 form)
DEVI v4f mfma16(v8bf a, v8bf b, v4f c) {
  return __builtin_amdgcn_mfma_f32_16x16x32_bf16(a, b, c, 0, 0, 0);
}
DEVI v8bf cvt2f(v4ff lo, v4ff hi) {
  v8bf r;
#pragma unroll
  for (int j = 0; j < 4; ++j) { r[j] = (__bf16)lo[j]; r[4 + j] = (__bf16)hi[j]; }
  return r;
}

// ---- prologue: convert all weight matrices f32 -> bf16 into d_ws ----
// Also builds W1F: fused padded head-W1, 16 out-cols x 256 K where
// K 0..127 = temphr activations, 128..255 = class activations.
__global__ void cvt_weights(const float* __restrict__ eWih, const float* __restrict__ eWhh,
                            const float* __restrict__ dWih, const float* __restrict__ dWhh,
                            const float* __restrict__ thW0, const float* __restrict__ thW1,
                            const float* __restrict__ clW0, const float* __restrict__ clW1,
                            u16* __restrict__ ws) {
  const int i = blockIdx.x * 256 + threadIdx.x;
  if (i >= W_TOTALF) return;
  if (i >= W_W1F) {
    const int r = i - W_W1F, c = r >> 8, k = r & 255;
    float v = 0.f;
    if (c < 2 && k < 128) v = thW1[c * 128 + k];
    else if (c >= 2 && c < FOUTC && k >= 128) v = clW1[(c - 2) * 128 + (k - 128)];
    ws[i] = f2bf(v);
    return;
  }
  const float* src; int off;
  if      (i < W_EWHH) { src = eWih; off = W_EWIH; }
  else if (i < W_DWIH) { src = eWhh; off = W_EWHH; }
  else if (i < W_DWHH) { src = dWih; off = W_DWIH; }
  else if (i < W_THW0) { src = dWhh; off = W_DWHH; }
  else if (i < W_THW1) { src = thW0; off = W_THW0; }
  else if (i < W_CLW0) { src = thW1; off = W_THW1; }
  else if (i < W_CLW1) { src = clW0; off = W_CLW0; }
  else                 { src = clW1; off = W_CLW1; }
  ws[i] = f2bf(src[i - off]);
}

// 512 threads = 8 waves @ 2 waves/SIMD (round-0 geometry: wave w owns gate
// col-tiles c = w, w+8; z,n Whh pinned in 128 AGPRs; 128 arch VGPRs clean).
// Round-6 change: the 132KB LDS r-gate slab is DELETED; r-gate Whh streams
// from L2 in the k-loop (16 ld8/wave/step, L2-hot: same 393KB re-read each
// step by all blocks). Rationale from r0 counters: per block-step the LDS
// pipe carried 192 ds_read_b128 (~2300cy) + 788 conflict cy ~= 29% of the
// 10.7k-cyc step, 2/3 of it slab reads, while the L2 path sat at ~20% use.
// A sched_barrier(0) at the k-loop midpoint caps in-flight weight loads at
// 8 (32 regs) to protect the 128-arch budget (spill tripwire: WRITE_SIZE).
// Also: bias-folded MFMA C-init and pre-padded W1F gemm2 (r4-verified).
__global__ __launch_bounds__(512, 2) void encdec_kernel(
    const float* __restrict__ xf, const float* __restrict__ yt, const float* __restrict__ pp,
    const float* __restrict__ ebih, const float* __restrict__ ebhh,
    const float* __restrict__ dbih, const float* __restrict__ dbhh,
    const float* __restrict__ thb0, const float* __restrict__ thb1,
    const float* __restrict__ clb0, const float* __restrict__ clb1,
    const u16* __restrict__ ws, float* __restrict__ outp) {
  __shared__ __align__(16) u16 hls[2][16 * HSTR];  // enc: h dbuf; dec: h=hls[0], a1#0=hls[1]
  __shared__ __align__(16) u16 a1x[16 * HSTR];     // a1 buffer #1
  __shared__ __align__(16) u16 uls[2][16 * UST2];

  const u16* eWih = ws + W_EWIH;
  const u16* eWhh = ws + W_EWHH;
  const u16* dWih = ws + W_DWIH;
  const u16* dWhh = ws + W_DWHH;
  const u16* thW0 = ws + W_THW0;
  const u16* clW0 = ws + W_CLW0;
  const u16* w1f  = ws + W_W1F;

  const int tid = threadIdx.x;
  const int wave = tid >> 6;        // 8 waves
  const int lane = tid & 63;
  const int col16 = lane & 15;
  const int quad = lane >> 4;
  const int n0 = blockIdx.x * 16;

  for (int i = tid; i < 16 * HSTR; i += 512) hls[0][i] = 0;

  float hreg[2][4];
#pragma unroll
  for (int j = 0; j < 2; ++j)
#pragma unroll
    for (int r = 0; r < 4; ++r) hreg[j][r] = 0.f;

  // Persistent (laundered -> AGPR): z,n Whh fragments (128 regs).
  v4f wz[2][8], wn[2][8];
  float bsr[2], bsz[2], bin_[2], bhn[2];

  const int mr0 = wave * 16 + col16;          // col-tile j=0 row in Whh
  const int mr1 = (wave + 8) * 16 + col16;    // col-tile j=1

  // ================= encoder phase =================
  {
#pragma unroll
    for (int j = 0; j < 2; ++j) {
      const int mr = (j == 0) ? mr0 : mr1;
      const int mz = 256 + mr, mn = 512 + mr;
#pragma unroll
      for (int k = 0; k < 8; ++k) {
        wz[j][k] = ldw(eWhh + (size_t)mz * HID + k * 32 + quad * 8); pin(wz[j][k]);
        wn[j][k] = ldw(eWhh + (size_t)mn * HID + k * 32 + quad * 8); pin(wn[j][k]);
      }
      bsr[j] = ebih[mr] + ebhh[mr];
      bsz[j] = ebih[mz] + ebhh[mz];
      bin_[j] = ebih[mn];
      bhn[j] = ebhh[mn];
    }
    const float* xbase = xf + (size_t)(n0 + col16) * LX * FF + quad * 8;
    const u16* wr0p = eWhh + (size_t)mr0 * HID + quad * 8;   // r-gate from L2
    const u16* wr1p = eWhh + (size_t)mr1 * HID + quad * 8;
    __syncthreads();  // h-init visible

#pragma unroll 1
    for (int t = 0; t < LX; ++t) {
      const float* xr = xbase + (size_t)t * FF;
      const v4ff x0 = *(const v4ff*)(xr);
      const v4ff x1 = *(const v4ff*)(xr + 4);
      const v4ff x2 = *(const v4ff*)(xr + 32);
      const v4ff x3 = *(const v4ff*)(xr + 36);
      const u16* hb = hls[t & 1] + col16 * HSTR + quad * 8;
      v8bf a[8];
#pragma unroll
      for (int k = 0; k < 8; ++k) a[k] = ld8(hb + k * 32);

      // 6 independent h-chains; bias-folded accumulator init;
      // r-gate B-frags stream from L2 (split in 2 batches by the fence)
      v4f az[2], ar[2], an[2];
#pragma unroll
      for (int j = 0; j < 2; ++j) {
        az[j] = (v4f){bsz[j], bsz[j], bsz[j], bsz[j]};
        ar[j] = (v4f){bsr[j], bsr[j], bsr[j], bsr[j]};
        an[j] = (v4f){bhn[j], bhn[j], bhn[j], bhn[j]};
      }
#pragma unroll
      for (int k = 0; k < 8; ++k) {
        if (k == 4) __builtin_amdgcn_sched_barrier(0);  // cap hoisted vmem batch
        az[0] = mfma16(a[k], asbf(wz[0][k]), az[0]);
        az[1] = mfma16(a[k], asbf(wz[1][k]), az[1]);
        ar[0] = mfma16(a[k], ld8(wr0p + k * 32), ar[0]);
        ar[1] = mfma16(a[k], ld8(wr1p + k * 32), ar[1]);
        an[0] = mfma16(a[k], asbf(wn[0][k]), an[0]);
        an[1] = mfma16(a[k], asbf(wn[1][k]), an[1]);
      }
      const v8bf xa0 = cvt2f(x0, x1);
      const v8bf xa1 = cvt2f(x2, x3);
      v4f ai[2];
#pragma unroll
      for (int j = 0; j < 2; ++j) {
        const int m = (wave + 8 * j) * 16 + col16;
        const u16* pwr = eWih + (size_t)m * FF + quad * 8;
        const u16* pwz = eWih + (size_t)(256 + m) * FF + quad * 8;
        const u16* pwn = eWih + (size_t)(512 + m) * FF + quad * 8;
        ai[j] = (v4f){bin_[j], bin_[j], bin_[j], bin_[j]};
        az[j] = mfma16(xa0, ld8(pwz), az[j]);
        az[j] = mfma16(xa1, ld8(pwz + 32), az[j]);
        ar[j] = mfma16(xa0, ld8(pwr), ar[j]);
        ar[j] = mfma16(xa1, ld8(pwr + 32), ar[j]);
        ai[j] = mfma16(xa0, ld8(pwn), ai[j]);
        ai[j] = mfma16(xa1, ld8(pwn + 32), ai[j]);
      }
#pragma unroll
      for (int j = 0; j < 2; ++j) {
        const int cidx = (wave + 8 * j) * 16 + col16;
#pragma unroll
        for (int r = 0; r < 4; ++r) {
          const float zg = sigm(az[j][r]);
          const float rg = sigm(ar[j][r]);
          const float ng = tanh_(ai[j][r] + rg * an[j][r]);
          hreg[j][r] = (1.f - zg) * ng + zg * hreg[j][r];
          hls[(t + 1) & 1][(quad * 4 + r) * HSTR + cidx] = f2bf(hreg[j][r]);
        }
      }
      __syncthreads();
    }
  }
  // h_enc in hls[LX & 1] == hls[0]  (LX even)

  // ================= decoder phase =================
  {
    float hb0[2];
#pragma unroll
    for (int j = 0; j < 2; ++j) {
      const int mr = (j == 0) ? mr0 : mr1;
      const int mz = 256 + mr, mn = 512 + mr;
#pragma unroll
      for (int k = 0; k < 8; ++k) {
        wz[j][k] = ldw(dWhh + (size_t)mz * HID + k * 32 + quad * 8); pin(wz[j][k]);
        wn[j][k] = ldw(dWhh + (size_t)mn * HID + k * 32 + quad * 8); pin(wn[j][k]);
      }
      bsr[j] = dbih[mr] + dbhh[mr];
      bsz[j] = dbih[mz] + dbhh[mz];
      bin_[j] = dbih[mn];
      bhn[j] = dbhh[mn];
      const int ml = wave * 16 + col16;
      hb0[j] = (j == 0) ? thb0[ml] : clb0[ml];
    }
    const float b1v = (col16 < 2) ? thb1[col16]
                    : (col16 < FOUTC) ? clb1[col16 - 2] : 0.f;
    const u16* w1p = w1f + col16 * HID + quad * 8;
    const u16* wr0p = dWhh + (size_t)mr0 * HID + quad * 8;   // r-gate from L2
    const u16* wr1p = dWhh + (size_t)mr1 * HID + quad * 8;

    const int srr = tid >> 5, scc = tid & 31;
    const size_t ybase = (size_t)(n0 + srr) * (LY + 1);
    {  // stage u_0 (src_t = 0)
      const float v = (scc < FT) ? yt[ybase * FT + scc] : pp[ybase * FOUTC + (scc - FT)];
      uls[0][srr * UST2 + scc] = f2bf(v);
    }

    // GEMM2 for step s: out(s) = a1(s) @ W1F^T + b1 (plain 8-chain).
    auto gemm2 = [&](int s, const u16* a1b) {
      const u16* arow = a1b + col16 * HSTR + quad * 8;
      v4f acc = {b1v, b1v, b1v, b1v};
#pragma unroll
      for (int kt = 0; kt < 8; ++kt)
        acc = mfma16(ld8(arow + kt * 32), ld8(w1p + kt * 32), acc);
      if (col16 < FOUTC) {
#pragma unroll
        for (int r = 0; r < 4; ++r)
          outp[((size_t)(n0 + quad * 4 + r) * LY + s) * FOUTC + col16] = acc[r];
      }
    };
    __syncthreads();  // u_0 visible (last h write already fenced)

#pragma unroll 1
    for (int t = 0; t < LY; ++t) {
      float un = 0.f;
      if (t + 1 < LY)
        un = (scc < FT) ? yt[(ybase + t) * FT + scc]
                        : pp[(ybase + t) * FOUTC + (scc - FT)];
      const v8bf ua = ld8(uls[t & 1] + col16 * UST2 + quad * 8);
      const u16* hb = hls[0] + col16 * HSTR + quad * 8;  // h_t (single buffer)
      v8bf a[8];
#pragma unroll
      for (int k = 0; k < 8; ++k) a[k] = ld8(hb + k * 32);
      __syncthreads();  // barR: all hls[0]/uls reads done before rewrites

      // GEMM2 for step t-2 (wave 0): reads a1 buffer written in slot t-1.
      if (wave == 0 && t >= 2) gemm2(t - 2, (t & 1) ? a1x : hls[1]);

      // gates (6 interleaved chains), bias-folded init, r from L2
      v4f az[2], ar[2], an[2];
#pragma unroll
      for (int j = 0; j < 2; ++j) {
        az[j] = (v4f){bsz[j], bsz[j], bsz[j], bsz[j]};
        ar[j] = (v4f){bsr[j], bsr[j], bsr[j], bsr[j]};
        an[j] = (v4f){bhn[j], bhn[j], bhn[j], bhn[j]};
      }
#pragma unroll
      for (int k = 0; k < 8; ++k) {
        if (k == 4) __builtin_amdgcn_sched_barrier(0);
        az[0] = mfma16(a[k], asbf(wz[0][k]), az[0]);
        az[1] = mfma16(a[k], asbf(wz[1][k]), az[1]);
        ar[0] = mfma16(a[k], ld8(wr0p + k * 32), ar[0]);
        ar[1] = mfma16(a[k], ld8(wr1p + k * 32), ar[1]);
        an[0] = mfma16(a[k], asbf(wn[0][k]), an[0]);
        an[1] = mfma16(a[k], asbf(wn[1][k]), an[1]);
      }
      v4f ai[2];
#pragma unroll
      for (int j = 0; j < 2; ++j) {
        const int m = (wave + 8 * j) * 16 + col16;
        ai[j] = (v4f){bin_[j], bin_[j], bin_[j], bin_[j]};
        az[j] = mfma16(ua, ld8(dWih + (size_t)(256 + m) * 32 + quad * 8), az[j]);
        ar[j] = mfma16(ua, ld8(dWih + (size_t)m * 32 + quad * 8), ar[j]);
        ai[j] = mfma16(ua, ld8(dWih + (size_t)(512 + m) * 32 + quad * 8), ai[j]);
      }
#pragma unroll
      for (int j = 0; j < 2; ++j) {
        const int cidx = (wave + 8 * j) * 16 + col16;
#pragma unroll
        for (int r = 0; r < 4; ++r) {
          const float zg = sigm(az[j][r]);
          const float rg = sigm(ar[j][r]);
          const float ng = tanh_(ai[j][r] + rg * an[j][r]);
          hreg[j][r] = (1.f - zg) * ng + zg * hreg[j][r];
          hls[0][(quad * 4 + r) * HSTR + cidx] = f2bf(hreg[j][r]);
        }
      }

      // GEMM1 for step t-1: a[] == h_t == h2_{t-1} (zero extra LDS reads)
      if (t >= 1) {
        u16* a1w = ((t - 1) & 1) ? a1x : hls[1];
#pragma unroll
        for (int j = 0; j < 2; ++j) {
          const u16* W0 = (j == 0) ? thW0 : clW0;
          const u16* pw = W0 + (size_t)(wave * 16 + col16) * HID + quad * 8;
          v4f acc = {hb0[j], hb0[j], hb0[j], hb0[j]};
#pragma unroll
          for (int k = 0; k < 8; ++k) acc = mfma16(a[k], ld8(pw + k * 32), acc);
          const int c = wave + 8 * j;
#pragma unroll
          for (int r = 0; r < 4; ++r)
            a1w[(quad * 4 + r) * HSTR + c * 16 + col16] = f2bf(smelu_(acc[r]));
        }
      }
      if (t + 1 < LY) uls[(t + 1) & 1][srr * UST2 + scc] = f2bf(un);
      __syncthreads();  // barW: h_{t+1}, u_{t+1}, a1(t-1) visible
    }

    // ---- epilogue: GEMM1(LY-1), GEMM2(LY-2), then GEMM2(LY-1) ----
    {
      const u16* h2b = hls[0] + col16 * HSTR + quad * 8;  // h_LY = h2_{LY-1}
      v8bf ah2[8];
#pragma unroll
      for (int k = 0; k < 8; ++k) ah2[k] = ld8(h2b + k * 32);
      u16* a1w = ((LY - 1) & 1) ? a1x : hls[1];           // = a1x (LY-1 odd)
#pragma unroll
      for (int j = 0; j < 2; ++j) {
        const u16* W0 = (j == 0) ? thW0 : clW0;
        const u16* pw = W0 + (size_t)(wave * 16 + col16) * HID + quad * 8;
        v4f acc = {hb0[j], hb0[j], hb0[j], hb0[j]};
#pragma unroll
        for (int k = 0; k < 8; ++k) acc = mfma16(ah2[k], ld8(pw + k * 32), acc);
        const int c = wave + 8 * j;
#pragma unroll
        for (int r = 0; r < 4; ++r)
          a1w[(quad * 4 + r) * HSTR + c * 16 + col16] = f2bf(smelu_(acc[r]));
      }
      if (wave == 0) gemm2(LY - 2, ((LY - 2) & 1) ? a1x : hls[1]);
      __syncthreads();
      if (wave == 0) gemm2(LY - 1, ((LY - 1) & 1) ? a1x : hls[1]);
    }
  }
}

extern "C" void kernel_launch(void* const* d_in, const int* in_sizes, int n_in,
                              void* d_out, int out_size, void* d_ws, size_t ws_size,
                              hipStream_t stream) {
  (void)in_sizes; (void)n_in; (void)ws_size; (void)out_size;
  const float* xf   = (const float*)d_in[0];
  // d_in[1] = x : unused by forward
  const float* yt   = (const float*)d_in[2];
  const float* pp   = (const float*)d_in[3];
  const float* eWih = (const float*)d_in[4];
  const float* eWhh = (const float*)d_in[5];
  const float* ebih = (const float*)d_in[6];
  const float* ebhh = (const float*)d_in[7];
  const float* dWih = (const float*)d_in[8];
  const float* dWhh = (const float*)d_in[9];
  const float* dbih = (const float*)d_in[10];
  const float* dbhh = (const float*)d_in[11];
  const float* thW0 = (const float*)d_in[12];
  const float* thb0 = (const float*)d_in[13];
  const float* thW1 = (const float*)d_in[14];
  const float* thb1 = (const float*)d_in[15];
  const float* clW0 = (const float*)d_in[16];
  const float* clb0 = (const float*)d_in[17];
  const float* clW1 = (const float*)d_in[18];
  const float* clb1 = (const float*)d_in[19];
  float* outp = (float*)d_out;
  u16* ws = (u16*)d_ws;  // needs W_TOTALF*2 ~= 1.05 MB of scratch

  cvt_weights<<<dim3((W_TOTALF + 255) / 256), dim3(256), 0, stream>>>(
      eWih, eWhh, dWih, dWhh, thW0, thW1, clW0, clW1, ws);
  encdec_kernel<<<dim3(128), dim3(512), 0, stream>>>(
      xf, yt, pp, ebih, ebhh, dbih, dbhh, thb0, thb1, clb0, clb1, ws, outp);
}

// Round 7
// 1406.716 us; speedup vs baseline: 1.5974x; 1.5974x over previous
//
#include <hip/hip_runtime.h>

typedef __bf16 v8bf __attribute__((ext_vector_type(8)));
typedef float v4f __attribute__((ext_vector_type(4)));
typedef float v4ff __attribute__((ext_vector_type(4)));
typedef unsigned short u16;
typedef unsigned int u32;

#define DEVI __device__ __forceinline__

constexpr int LX = 168, FF = 64;
constexpr int LY = 72, FT = 22, FOUTC = 10;
constexpr int HID = 256;
constexpr int HSTR = 264;   // u16/row for 16x256 tiles (528B = 33*16)
constexpr int UST2 = 40;
constexpr int SSTR = 264;   // slab row stride (r-gate Whh rows 0..255)

// bf16 weight cache layout in d_ws (u16 element offsets; all 16B-aligned)
constexpr int W_EWIH = 0;                      // 768*64
constexpr int W_EWHH = 49152;                  // 768*256
constexpr int W_DWIH = 245760;                 // 768*32
constexpr int W_DWHH = 270336;                 // 768*256
constexpr int W_THW0 = 466944;                 // 128*256
constexpr int W_THW1 = 499712;                 // 2*128
constexpr int W_CLW0 = 499968;                 // 128*256
constexpr int W_CLW1 = 532736;                 // 8*128
constexpr int W_W1F  = 533760;                 // fused padded W1: 16 x 256
constexpr int W_TOTALF = 537856;               // incl. W1F

// Native RNE cast (bit-identical to the manual round-nearest-even f2bf, but
// lets the compiler pair casts into v_cvt_pk_bf16_f32: ~28 VALU/thread/step).
DEVI u16 f2bf(float f) {
  __bf16 b = (__bf16)f;
  u16 r; __builtin_memcpy(&r, &b, 2);
  return r;
}
DEVI float sigm(float x) { return __builtin_amdgcn_rcpf(1.f + __expf(-x)); }
DEVI float tanh_(float x) {
  float e = __expf(-2.f * fabsf(x));
  return copysignf((1.f - e) * __builtin_amdgcn_rcpf(1.f + e), x);
}
DEVI float smelu_(float x) {
  if (x >= 1.1f) return x;
  if (x <= -1.1f) return 0.f;
  float u = x + 1.1f;
  return u * u * (1.f / 4.4f);
}
DEVI v8bf ld8(const u16* p) { return *reinterpret_cast<const v8bf*>(p); }
DEVI v4f ldw(const u16* p) { return *reinterpret_cast<const v4f*>(p); }
DEVI v8bf asbf(v4f x) { return __builtin_bit_cast(v8bf, x); }
DEVI void pin(v4f& x) { asm("" : "+v"(x)); }       // defeat rematerialization
DEVI v4f mfma16(v8bf a, v8bf b, v4f c) {
  return __builtin_amdgcn_mfma_f32_16x16x32_bf16(a, b, c, 0, 0, 0);
}
DEVI v8bf cvt2f(v4ff lo, v4ff hi) {
  v8bf r;
#pragma unroll
  for (int j = 0; j < 4; ++j) { r[j] = (__bf16)lo[j]; r[4 + j] = (__bf16)hi[j]; }
  return r;
}

// ---- prologue: convert all weight matrices f32 -> bf16 into d_ws ----
// Also builds W1F: fused padded head-W1, 16 out-cols x 256 K where
// K 0..127 = temphr activations, 128..255 = class activations. (r4-verified)
__global__ void cvt_weights(const float* __restrict__ eWih, const float* __restrict__ eWhh,
                            const float* __restrict__ dWih, const float* __restrict__ dWhh,
                            const float* __restrict__ thW0, const float* __restrict__ thW1,
                            const float* __restrict__ clW0, const float* __restrict__ clW1,
                            u16* __restrict__ ws) {
  const int i = blockIdx.x * 256 + threadIdx.x;
  if (i >= W_TOTALF) return;
  if (i >= W_W1F) {
    const int r = i - W_W1F, c = r >> 8, k = r & 255;
    float v = 0.f;
    if (c < 2 && k < 128) v = thW1[c * 128 + k];
    else if (c >= 2 && c < FOUTC && k >= 128) v = clW1[(c - 2) * 128 + (k - 128)];
    ws[i] = f2bf(v);
    return;
  }
  const float* src; int off;
  if      (i < W_EWHH) { src = eWih; off = W_EWIH; }
  else if (i < W_DWIH) { src = eWhh; off = W_EWHH; }
  else if (i < W_DWHH) { src = dWih; off = W_DWIH; }
  else if (i < W_THW0) { src = dWhh; off = W_DWHH; }
  else if (i < W_THW1) { src = thW0; off = W_THW0; }
  else if (i < W_CLW0) { src = thW1; off = W_THW1; }
  else if (i < W_CLW1) { src = clW0; off = W_CLW0; }
  else                 { src = clW1; off = W_CLW1; }
  ws[i] = f2bf(src[i - off]);
}

// Round-7: r0 structure (512 thr / 8 waves / 2 waves/SIMD / slab in LDS /
// z,n pinned 128 regs) but M=8: 256 blocks x 8 batch rows -> all 256 CUs.
// Rows 8..15 of every 16-row tile are garbage (zero-filled, never stored):
// they are quads 2,3 = lanes 32..63 = exactly the upper half-wave, so the
// pointwise/ds_write/output mask `quad < 2` leaves EXEC hi-32 = 0 (masked
// lanes issue no LDS bank requests; upper-half pass may be skipped).
// Per-block weight-stream cost (slab reads, k-loop MFMA) is M-independent;
// the M-dependent VALU/write portion halves. Bundled (all HW-verified):
// bias-folded C-init (r2), W1F gemm2 (r4/r6), native bf16 casts.
__global__ __launch_bounds__(512, 2) void encdec_kernel(
    const float* __restrict__ xf, const float* __restrict__ yt, const float* __restrict__ pp,
    const float* __restrict__ ebih, const float* __restrict__ ebhh,
    const float* __restrict__ dbih, const float* __restrict__ dbhh,
    const float* __restrict__ thb0, const float* __restrict__ thb1,
    const float* __restrict__ clb0, const float* __restrict__ clb1,
    const u16* __restrict__ ws, float* __restrict__ outp) {
  __shared__ __align__(16) u16 slab[256 * SSTR];   // r-gate Whh rows (132 KB)
  __shared__ __align__(16) u16 hls[2][16 * HSTR];  // enc: h dbuf; dec: h=hls[0], a1#0=hls[1]
  __shared__ __align__(16) u16 a1x[16 * HSTR];     // a1 buffer #1
  __shared__ __align__(16) u16 uls[2][16 * UST2];

  const u16* eWih = ws + W_EWIH;
  const u16* eWhh = ws + W_EWHH;
  const u16* dWih = ws + W_DWIH;
  const u16* dWhh = ws + W_DWHH;
  const u16* thW0 = ws + W_THW0;
  const u16* clW0 = ws + W_CLW0;
  const u16* w1f  = ws + W_W1F;

  const int tid = threadIdx.x;
  const int wave = tid >> 6;        // 8 waves
  const int lane = tid & 63;
  const int col16 = lane & 15;
  const int quad = lane >> 4;
  const int n0 = blockIdx.x * 8;    // M=8 rows per block

  // zero ALL exchange buffers once: garbage rows (8..15) stay 0 forever
  for (int i = tid; i < 16 * HSTR; i += 512) {
    hls[0][i] = 0; hls[1][i] = 0; a1x[i] = 0;
  }

  float hreg[2][4];
#pragma unroll
  for (int j = 0; j < 2; ++j)
#pragma unroll
    for (int r = 0; r < 4; ++r) hreg[j][r] = 0.f;

  // Persistent (laundered -> AGPR): z,n Whh fragments (128 regs).
  v4f wz[2][8], wn[2][8];
  float bsr[2], bsz[2], bin_[2], bhn[2];

  // ================= encoder phase =================
  {
    for (int i = tid; i < 256 * 32; i += 512) {  // stage r-gate Whh slab
      const int row = i >> 5, kb = (i & 31) << 3;
      *reinterpret_cast<v8bf*>(&slab[row * SSTR + kb]) = ld8(eWhh + row * HID + kb);
    }
#pragma unroll
    for (int j = 0; j < 2; ++j) {
      const int c = wave + 8 * j;
      const int mr = c * 16 + col16, mz = 256 + mr, mn = 512 + mr;
#pragma unroll
      for (int k = 0; k < 8; ++k) {
        wz[j][k] = ldw(eWhh + (size_t)mz * HID + k * 32 + quad * 8); pin(wz[j][k]);
        wn[j][k] = ldw(eWhh + (size_t)mn * HID + k * 32 + quad * 8); pin(wn[j][k]);
      }
      bsr[j] = ebih[mr] + ebhh[mr];
      bsz[j] = ebih[mz] + ebhh[mz];
      bin_[j] = ebih[mn];
      bhn[j] = ebhh[mn];
    }
    // x row clamp: lanes col16>=8 duplicate row (col16&7) (finite garbage)
    const float* xbase = xf + (size_t)(n0 + (col16 & 7)) * LX * FF + quad * 8;
    const u16* sp0 = slab + (wave * 16 + col16) * SSTR + quad * 8;
    const u16* sp1 = slab + ((wave + 8) * 16 + col16) * SSTR + quad * 8;
    __syncthreads();  // slab + buffer-init visible

#pragma unroll 1
    for (int t = 0; t < LX; ++t) {
      const float* xr = xbase + (size_t)t * FF;
      const v4ff x0 = *(const v4ff*)(xr);
      const v4ff x1 = *(const v4ff*)(xr + 4);
      const v4ff x2 = *(const v4ff*)(xr + 32);
      const v4ff x3 = *(const v4ff*)(xr + 36);
      const u16* hb = hls[t & 1] + col16 * HSTR + quad * 8;
      v8bf a[8];
#pragma unroll
      for (int k = 0; k < 8; ++k) a[k] = ld8(hb + k * 32);

      // 6 independent h-chains, k-outer interleave; bias-folded C-init
      v4f az[2], ar[2], an[2], ai[2];
#pragma unroll
      for (int j = 0; j < 2; ++j) {
        az[j] = (v4f){bsz[j], bsz[j], bsz[j], bsz[j]};
        ar[j] = (v4f){bsr[j], bsr[j], bsr[j], bsr[j]};
        an[j] = (v4f){bhn[j], bhn[j], bhn[j], bhn[j]};
        ai[j] = (v4f){bin_[j], bin_[j], bin_[j], bin_[j]};
      }
#pragma unroll
      for (int k = 0; k < 8; ++k) {
        az[0] = mfma16(a[k], asbf(wz[0][k]), az[0]);
        az[1] = mfma16(a[k], asbf(wz[1][k]), az[1]);
        ar[0] = mfma16(a[k], ld8(sp0 + k * 32), ar[0]);
        ar[1] = mfma16(a[k], ld8(sp1 + k * 32), ar[1]);
        an[0] = mfma16(a[k], asbf(wn[0][k]), an[0]);
        an[1] = mfma16(a[k], asbf(wn[1][k]), an[1]);
      }
      const v8bf xa0 = cvt2f(x0, x1);
      const v8bf xa1 = cvt2f(x2, x3);
#pragma unroll
      for (int j = 0; j < 2; ++j) {
        const int m = (wave + 8 * j) * 16 + col16;
        const u16* pwr = eWih + (size_t)m * FF + quad * 8;
        const u16* pwz = eWih + (size_t)(256 + m) * FF + quad * 8;
        const u16* pwn = eWih + (size_t)(512 + m) * FF + quad * 8;
        az[j] = mfma16(xa0, ld8(pwz), az[j]);
        az[j] = mfma16(xa1, ld8(pwz + 32), az[j]);
        ar[j] = mfma16(xa0, ld8(pwr), ar[j]);
        ar[j] = mfma16(xa1, ld8(pwr + 32), ar[j]);
        ai[j] = mfma16(xa0, ld8(pwn), ai[j]);
        ai[j] = mfma16(xa1, ld8(pwn + 32), ai[j]);
      }
      // pointwise: real rows only (quads 0,1 = lanes 0..31; hi half-wave idle)
      if (quad < 2) {
#pragma unroll
        for (int j = 0; j < 2; ++j) {
          const int cidx = (wave + 8 * j) * 16 + col16;
#pragma unroll
          for (int r = 0; r < 4; ++r) {
            const float zg = sigm(az[j][r]);
            const float rg = sigm(ar[j][r]);
            const float ng = tanh_(ai[j][r] + rg * an[j][r]);
            hreg[j][r] = (1.f - zg) * ng + zg * hreg[j][r];
            hls[(t + 1) & 1][(quad * 4 + r) * HSTR + cidx] = f2bf(hreg[j][r]);
          }
        }
      }
      __syncthreads();
    }
  }
  // h_enc in hls[LX & 1] == hls[0]  (LX even)

  // ================= decoder phase =================
  {
    for (int i = tid; i < 256 * 32; i += 512) {  // restage slab with dWhh r rows
      const int row = i >> 5, kb = (i & 31) << 3;
      *reinterpret_cast<v8bf*>(&slab[row * SSTR + kb]) = ld8(dWhh + row * HID + kb);
    }
    float hb0[2];
#pragma unroll
    for (int j = 0; j < 2; ++j) {
      const int c = wave + 8 * j;
      const int mr = c * 16 + col16, mz = 256 + mr, mn = 512 + mr;
#pragma unroll
      for (int k = 0; k < 8; ++k) {
        wz[j][k] = ldw(dWhh + (size_t)mz * HID + k * 32 + quad * 8); pin(wz[j][k]);
        wn[j][k] = ldw(dWhh + (size_t)mn * HID + k * 32 + quad * 8); pin(wn[j][k]);
      }
      bsr[j] = dbih[mr] + dbhh[mr];
      bsz[j] = dbih[mz] + dbhh[mz];
      bin_[j] = dbih[mn];
      bhn[j] = dbhh[mn];
      const int ml = wave * 16 + col16;
      hb0[j] = (j == 0) ? thb0[ml] : clb0[ml];
    }
    const float b1v = (col16 < 2) ? thb1[col16]
                    : (col16 < FOUTC) ? clb1[col16 - 2] : 0.f;
    const u16* w1p = w1f + col16 * HID + quad * 8;
    const u16* sp0 = slab + (wave * 16 + col16) * SSTR + quad * 8;
    const u16* sp1 = slab + ((wave + 8) * 16 + col16) * SSTR + quad * 8;

    const int srr = tid >> 5, scc = tid & 31;
    // u row clamp: staging rows 8..15 duplicate rows 0..7 (finite garbage)
    const size_t ybase = (size_t)(n0 + (srr & 7)) * (LY + 1);
    {  // stage u_0 (src_t = 0)
      const float v = (scc < FT) ? yt[ybase * FT + scc] : pp[ybase * FOUTC + (scc - FT)];
      uls[0][srr * UST2 + scc] = f2bf(v);
    }

    // GEMM2 for step s: out(s) = a1(s) @ W1F^T + b1 (plain 8-chain, r6-verified)
    auto gemm2 = [&](int s, const u16* a1b) {
      const u16* arow = a1b + col16 * HSTR + quad * 8;
      v4f acc = {b1v, b1v, b1v, b1v};
#pragma unroll
      for (int kt = 0; kt < 8; ++kt)
        acc = mfma16(ld8(arow + kt * 32), ld8(w1p + kt * 32), acc);
      if (col16 < FOUTC && quad < 2) {
#pragma unroll
        for (int r = 0; r < 4; ++r)
          outp[((size_t)(n0 + quad * 4 + r) * LY + s) * FOUTC + col16] = acc[r];
      }
    };
    __syncthreads();  // slab + u_0 visible (also last h write already fenced)

#pragma unroll 1
    for (int t = 0; t < LY; ++t) {
      float un = 0.f;
      if (t + 1 < LY)
        un = (scc < FT) ? yt[(ybase + t) * FT + scc]
                        : pp[(ybase + t) * FOUTC + (scc - FT)];
      const v8bf ua = ld8(uls[t & 1] + col16 * UST2 + quad * 8);
      const u16* hb = hls[0] + col16 * HSTR + quad * 8;  // h_t (single buffer)
      v8bf a[8];
#pragma unroll
      for (int k = 0; k < 8; ++k) a[k] = ld8(hb + k * 32);
      __syncthreads();  // barR: all hls[0]/uls reads done before rewrites

      // GEMM2 for step t-2 (wave 0): reads a1 buffer written in slot t-1.
      if (wave == 0 && t >= 2) gemm2(t - 2, (t & 1) ? a1x : hls[1]);

      // gates (6 interleaved chains), bias-folded C-init
      v4f az[2], ar[2], an[2], ai[2];
#pragma unroll
      for (int j = 0; j < 2; ++j) {
        az[j] = (v4f){bsz[j], bsz[j], bsz[j], bsz[j]};
        ar[j] = (v4f){bsr[j], bsr[j], bsr[j], bsr[j]};
        an[j] = (v4f){bhn[j], bhn[j], bhn[j], bhn[j]};
        ai[j] = (v4f){bin_[j], bin_[j], bin_[j], bin_[j]};
      }
#pragma unroll
      for (int k = 0; k < 8; ++k) {
        az[0] = mfma16(a[k], asbf(wz[0][k]), az[0]);
        az[1] = mfma16(a[k], asbf(wz[1][k]), az[1]);
        ar[0] = mfma16(a[k], ld8(sp0 + k * 32), ar[0]);
        ar[1] = mfma16(a[k], ld8(sp1 + k * 32), ar[1]);
        an[0] = mfma16(a[k], asbf(wn[0][k]), an[0]);
        an[1] = mfma16(a[k], asbf(wn[1][k]), an[1]);
      }
#pragma unroll
      for (int j = 0; j < 2; ++j) {
        const int m = (wave + 8 * j) * 16 + col16;
        az[j] = mfma16(ua, ld8(dWih + (size_t)(256 + m) * 32 + quad * 8), az[j]);
        ar[j] = mfma16(ua, ld8(dWih + (size_t)m * 32 + quad * 8), ar[j]);
        ai[j] = mfma16(ua, ld8(dWih + (size_t)(512 + m) * 32 + quad * 8), ai[j]);
      }
      if (quad < 2) {
#pragma unroll
        for (int j = 0; j < 2; ++j) {
          const int cidx = (wave + 8 * j) * 16 + col16;
#pragma unroll
          for (int r = 0; r < 4; ++r) {
            const float zg = sigm(az[j][r]);
            const float rg = sigm(ar[j][r]);
            const float ng = tanh_(ai[j][r] + rg * an[j][r]);
            hreg[j][r] = (1.f - zg) * ng + zg * hreg[j][r];
            hls[0][(quad * 4 + r) * HSTR + cidx] = f2bf(hreg[j][r]);
          }
        }
      }

      // GEMM1 for step t-1: a[] == h_t == h2_{t-1} (zero extra LDS reads)
      if (t >= 1) {
        u16* a1w = ((t - 1) & 1) ? a1x : hls[1];
#pragma unroll
        for (int j = 0; j < 2; ++j) {
          const u16* W0 = (j == 0) ? thW0 : clW0;
          const u16* pw = W0 + (size_t)(wave * 16 + col16) * HID + quad * 8;
          v4f acc = {hb0[j], hb0[j], hb0[j], hb0[j]};
#pragma unroll
          for (int k = 0; k < 8; ++k) acc = mfma16(a[k], ld8(pw + k * 32), acc);
          if (quad < 2) {
            const int c = wave + 8 * j;
#pragma unroll
            for (int r = 0; r < 4; ++r)
              a1w[(quad * 4 + r) * HSTR + c * 16 + col16] = f2bf(smelu_(acc[r]));
          }
        }
      }
      if (t + 1 < LY) uls[(t + 1) & 1][srr * UST2 + scc] = f2bf(un);
      __syncthreads();  // barW: h_{t+1}, u_{t+1}, a1(t-1) visible
    }

    // ---- epilogue: GEMM1(LY-1), GEMM2(LY-2), then GEMM2(LY-1) ----
    {
      const u16* h2b = hls[0] + col16 * HSTR + quad * 8;  // h_LY = h2_{LY-1}
      v8bf ah2[8];
#pragma unroll
      for (int k = 0; k < 8; ++k) ah2[k] = ld8(h2b + k * 32);
      u16* a1w = ((LY - 1) & 1) ? a1x : hls[1];           // = a1x (LY-1 odd)
#pragma unroll
      for (int j = 0; j < 2; ++j) {
        const u16* W0 = (j == 0) ? thW0 : clW0;
        const u16* pw = W0 + (size_t)(wave * 16 + col16) * HID + quad * 8;
        v4f acc = {hb0[j], hb0[j], hb0[j], hb0[j]};
#pragma unroll
        for (int k = 0; k < 8; ++k) acc = mfma16(ah2[k], ld8(pw + k * 32), acc);
        if (quad < 2) {
          const int c = wave + 8 * j;
#pragma unroll
          for (int r = 0; r < 4; ++r)
            a1w[(quad * 4 + r) * HSTR + c * 16 + col16] = f2bf(smelu_(acc[r]));
        }
      }
      if (wave == 0) gemm2(LY - 2, ((LY - 2) & 1) ? a1x : hls[1]);
      __syncthreads();
      if (wave == 0) gemm2(LY - 1, ((LY - 1) & 1) ? a1x : hls[1]);
    }
  }
}

extern "C" void kernel_launch(void* const* d_in, const int* in_sizes, int n_in,
                              void* d_out, int out_size, void* d_ws, size_t ws_size,
                              hipStream_t stream) {
  (void)in_sizes; (void)n_in; (void)ws_size; (void)out_size;
  const float* xf   = (const float*)d_in[0];
  // d_in[1] = x : unused by forward
  const float* yt   = (const float*)d_in[2];
  const float* pp   = (const float*)d_in[3];
  const float* eWih = (const float*)d_in[4];
  const float* eWhh = (const float*)d_in[5];
  const float* ebih = (const float*)d_in[6];
  const float* ebhh = (const float*)d_in[7];
  const float* dWih = (const float*)d_in[8];
  const float* dWhh = (const float*)d_in[9];
  const float* dbih = (const float*)d_in[10];
  const float* dbhh = (const float*)d_in[11];
  const float* thW0 = (const float*)d_in[12];
  const float* thb0 = (const float*)d_in[13];
  const float* thW1 = (const float*)d_in[14];
  const float* thb1 = (const float*)d_in[15];
  const float* clW0 = (const float*)d_in[16];
  const float* clb0 = (const float*)d_in[17];
  const float* clW1 = (const float*)d_in[18];
  const float* clb1 = (const float*)d_in[19];
  float* outp = (float*)d_out;
  u16* ws = (u16*)d_ws;  // needs W_TOTALF*2 ~= 1.05 MB of scratch

  cvt_weights<<<dim3((W_TOTALF + 255) / 256), dim3(256), 0, stream>>>(
      eWih, eWhh, dWih, dWhh, thW0, thW1, clW0, clW1, ws);
  encdec_kernel<<<dim3(256), dim3(512), 0, stream>>>(
      xf, yt, pp, ebih, ebhh, dbih, dbhh, thb0, thb1, clb0, clb1, ws, outp);
}